// Round 1
// baseline (667.310 us; speedup 1.0000x reference)
//
#include <hip/hip_runtime.h>

#define HID 128
#define NTY 8
#define SCAP 768   // LDS staging capacity for block src indices

typedef __attribute__((ext_vector_type(8))) short bf16x8;
typedef __attribute__((ext_vector_type(4))) float f32x4;

__device__ __forceinline__ unsigned short f2bf(float x) {
    unsigned u = __float_as_uint(x);
    u += 0x7FFF + ((u >> 16) & 1);          // RNE
    return (unsigned short)(u >> 16);
}
__device__ __forceinline__ float bf2f(unsigned short s) {
    return __uint_as_float(((unsigned)s) << 16);
}
__device__ __forceinline__ float sigmoidf_fast(float x) {
    return 1.f / (1.f + __expf(-x));
}
__device__ __forceinline__ float tanhf_fast(float x) {
    return 1.f - 2.f / (1.f + __expf(2.f * x));
}

// ---------------- dtype prep ----------------
__global__ void conv_h_kernel(const float* __restrict__ h, unsigned short* __restrict__ hbf, int n) {
    int i = blockIdx.x * 256 + threadIdx.x;
    if (i < n) hbf[i] = f2bf(h[i]);
}

// Message weights in per-lane-contiguous MFMA fragment order:
// wfr[(t*64+lane)*256 + (cb*4+kc)*8 + e] = bf16( W[t][k][d] ),
//   lane=(quad<<4)|lr, d=cb*16+lr, k=kc*32+quad*8+e
__global__ void conv_Wfrag_kernel(const float* __restrict__ W, unsigned short* __restrict__ wfr) {
    int i = blockIdx.x * 256 + threadIdx.x;   // 8*64*32*8 = 131072
    int e = i & 7, f = (i >> 3) & 31, lane = (i >> 8) & 63, t = i >> 14;
    int cb = f >> 2, kc = f & 3;
    int lr = lane & 15, quad = lane >> 4;
    int d = cb * 16 + lr;
    int k = kc * 32 + quad * 8 + e;
    wfr[i] = f2bf(W[(t << 14) + (k << 7) + d]);
}

// GRU weights in per-lane-contiguous fragment order:
// wpkf[(lane*192 + kc*24 + g3*8 + ct)*8 + e]; kc<4 -> wih (m half), kc>=4 -> whh (h half)
//   d = ct*16+lr, kk = quad*8+e
__global__ void conv_wpkf_kernel(const float* __restrict__ wih, const float* __restrict__ whh,
                                 unsigned short* __restrict__ wpkf) {
    int i = blockIdx.x * 256 + threadIdx.x;   // 64*192*8 = 98304
    int e = i & 7;
    int rest = i >> 3;
    int lane = rest / 192;
    int f = rest - lane * 192;
    int kc = f / 24;
    int f2 = f - kc * 24;
    int g3 = f2 >> 3, ct = f2 & 7;
    int lr = lane & 15, quad = lane >> 4;
    int d = ct * 16 + lr;
    int kk = quad * 8 + e;
    float v;
    if (kc < 4) v = wih[(g3 * 128 + d) * 128 + kc * 32 + kk];
    else        v = whh[(g3 * 128 + d) * 128 + (kc - 4) * 32 + kk];
    wpkf[i] = f2bf(v);
}

// ---------------- counting sort by key = dst*8 + type ----------------
__global__ void hist8_kernel(const int* __restrict__ etype, const int* __restrict__ ei,
                             int E, int* __restrict__ deg8) {
    int stride = gridDim.x * blockDim.x;
    for (int i = blockIdx.x * blockDim.x + threadIdx.x; i < E; i += stride)
        atomicAdd(&deg8[ei[E + i] * 8 + etype[i]], 1);
}

__global__ void scanA_kernel(const int* __restrict__ deg, int* __restrict__ start,
                             int* __restrict__ bsum, int N) {
    __shared__ int s[256];
    int i = blockIdx.x * 256 + threadIdx.x;
    int v = (i < N) ? deg[i] : 0;
    s[threadIdx.x] = v;
    __syncthreads();
    for (int off = 1; off < 256; off <<= 1) {
        int t = (threadIdx.x >= off) ? s[threadIdx.x - off] : 0;
        __syncthreads();
        s[threadIdx.x] += t;
        __syncthreads();
    }
    if (i < N) start[i] = s[threadIdx.x] - v;
    if (threadIdx.x == 255) bsum[blockIdx.x] = s[255];
}

// generic single-block scan for up to 256*C block sums
__global__ void scanBbig_kernel(int* __restrict__ bsum, int nb) {
    __shared__ int s[256];
    int tx = threadIdx.x;
    int C = (nb + 255) / 256;
    int lo = tx * C, hi = lo + C; if (hi > nb) hi = nb;
    int sum = 0;
    for (int j = lo; j < hi; ++j) sum += bsum[j];
    s[tx] = sum;
    __syncthreads();
    for (int off = 1; off < 256; off <<= 1) {
        int t = (tx >= off) ? s[tx - off] : 0;
        __syncthreads();
        s[tx] += t;
        __syncthreads();
    }
    int run = s[tx] - sum;
    for (int j = lo; j < hi; ++j) { int v = bsum[j]; bsum[j] = run; run += v; }
}

__global__ void scanC8_kernel(int* __restrict__ start8, const int* __restrict__ bsum,
                              int* __restrict__ cur8, int M8, int E) {
    int i = blockIdx.x * 256 + threadIdx.x;
    if (i < M8) {
        int v = start8[i] + bsum[blockIdx.x];
        start8[i] = v;
        cur8[i] = v;
    }
    if (i == 0) start8[M8] = E;
}

__global__ void scatter8_kernel(const int* __restrict__ etype, const int* __restrict__ ei,
                                int E, int* __restrict__ cur8, int* __restrict__ sortedE) {
    int stride = gridDim.x * blockDim.x;
    for (int i = blockIdx.x * blockDim.x + threadIdx.x; i < E; i += stride) {
        int pos = atomicAdd(&cur8[ei[E + i] * 8 + etype[i]], 1);
        sortedE[pos] = ei[i];   // store src node id directly
    }
}

// ---------------- fused aggregate -> per-type transform -> GRU ----------------
// messages[v] = sum_t W_t * (sum_{e in (v,t)} h[src_e]) + cnt(v,t)*b_t   (linearity)
// Block: 64 nodes, 4 waves x 16 nodes. No M tensor, no msg_gemm.
__global__ __launch_bounds__(256) void fused_ggnn(
    const unsigned short* __restrict__ hbf, const float* __restrict__ hf,
    const int* __restrict__ sortedE, const int* __restrict__ start8,
    const unsigned short* __restrict__ wfr, const float* __restrict__ bias,
    const unsigned short* __restrict__ wpkf, const float* __restrict__ bih,
    const float* __restrict__ bhh, float* __restrict__ out, int N)
{
    __shared__ unsigned short As[4][2048];   // per-wave 16x128 bf16 msg, XOR-swizzled
    __shared__ int srcs[SCAP];
    __shared__ int bnds[513];

    int tx = threadIdx.x;
    int n0 = blockIdx.x * 64;
    int lane = tx & 63, w = tx >> 6;
    int lr = lane & 15, quad = lane >> 4;
    int ln = w * 16 + lr;          // local node index 0..63
    int n = n0 + ln;
    bool valid = (n < N);
    int nc = valid ? n : (N - 1);

    int nhi = n0 + 64; if (nhi > N) nhi = N;
    int rowlo = start8[n0 * 8];
    int rowhi = start8[nhi * 8];
    int cntb = rowhi - rowlo;

    // stage block's src ids + segment bounds into LDS
    for (int i = tx; i < cntb && i < SCAP; i += 256) srcs[i] = sortedE[rowlo + i];
    int top = (nhi - n0) * 8;
    for (int i = tx; i <= top; i += 256) bnds[i] = start8[n0 * 8 + i];
    __syncthreads();

    const int* rbase = (cntb <= SCAP) ? (const int*)srcs : sortedE;
    int roff = (cntb <= SCAP) ? rowlo : 0;

    // ---- phase 1: per-type aggregate + MFMA transform ----
    f32x4 macc[8] = {};   // msg[node=lr][d = cb*16 + quad*4 + j]
    const unsigned short* wl = wfr + ((size_t)lane << 8);

    for (int t = 0; t < 8; ++t) {
        int rs = valid ? bnds[ln * 8 + t] : 0;
        int re = valid ? bnds[ln * 8 + t + 1] : 0;

        float sa[32];
        #pragma unroll
        for (int j = 0; j < 32; ++j) sa[j] = 0.f;

        for (int r = rs; r < re; ++r) {
            int src = rbase[r - roff];
            const unsigned short* hp = hbf + ((size_t)src << 7) + (quad << 3);
            uint4 v0 = *(const uint4*)(hp);
            uint4 v1 = *(const uint4*)(hp + 32);
            uint4 v2 = *(const uint4*)(hp + 64);
            uint4 v3 = *(const uint4*)(hp + 96);
            const unsigned short* p0 = (const unsigned short*)&v0;
            const unsigned short* p1 = (const unsigned short*)&v1;
            const unsigned short* p2 = (const unsigned short*)&v2;
            const unsigned short* p3 = (const unsigned short*)&v3;
            #pragma unroll
            for (int u = 0; u < 8; ++u) {
                sa[u]      += bf2f(p0[u]);
                sa[8 + u]  += bf2f(p1[u]);
                sa[16 + u] += bf2f(p2[u]);
                sa[24 + u] += bf2f(p3[u]);
            }
        }

        // count-scaled bias
        float fcnt = (float)(re - rs);
        #pragma unroll
        for (int cb = 0; cb < 8; ++cb) {
            float4 bv = *(const float4*)&bias[t * 128 + cb * 16 + quad * 4];
            macc[cb][0] += fcnt * bv.x;
            macc[cb][1] += fcnt * bv.y;
            macc[cb][2] += fcnt * bv.z;
            macc[cb][3] += fcnt * bv.w;
        }

        // transform: macc += W_t * S_t
        const unsigned short* wlt = wl + t * 16384;
        #pragma unroll
        for (int kc = 0; kc < 4; ++kc) {
            unsigned short au[8];
            #pragma unroll
            for (int u = 0; u < 8; ++u) au[u] = f2bf(sa[kc * 8 + u]);
            bf16x8 af = *(const bf16x8*)au;
            #pragma unroll
            for (int cb = 0; cb < 8; ++cb) {
                bf16x8 wf = *(const bf16x8*)&wlt[(cb * 4 + kc) * 8];
                macc[cb] = __builtin_amdgcn_mfma_f32_16x16x32_bf16(wf, af, macc[cb], 0, 0, 0);
            }
        }
    }

    // ---- write msg (bf16) to per-wave LDS, XOR-swizzled rows ----
    unsigned short* AsW = &As[w][0];
    #pragma unroll
    for (int cb = 0; cb < 8; ++cb) {
        uint2 v;
        v.x = (unsigned)f2bf(macc[cb][0]) | ((unsigned)f2bf(macc[cb][1]) << 16);
        v.y = (unsigned)f2bf(macc[cb][2]) | ((unsigned)f2bf(macc[cb][3]) << 16);
        int byte = (lr << 8) + (cb << 5) + (quad << 3);
        byte ^= (lr & 7) << 4;
        *(uint2*)((char*)AsW + byte) = v;
    }
    __syncthreads();

    // ---- GRU phase: sequential gates, d-half split (low live-acc count) ----
    bf16x8 afh[4];   // h fragments, cached
    {
        const unsigned short* hrow = hbf + ((size_t)nc << 7) + (quad << 3);
        #pragma unroll
        for (int k4 = 0; k4 < 4; ++k4) afh[k4] = *(const bf16x8*)&hrow[k4 * 32];
    }
    const unsigned short* wp = wpkf + (size_t)lane * 1536;

    #pragma unroll
    for (int dh = 0; dh < 2; ++dh) {
        f32x4 aR[4] = {}, aZ[4] = {}, aH[4] = {};
        #pragma unroll
        for (int kc = 0; kc < 8; ++kc) {
            bf16x8 af;
            if (kc < 4) {
                int byte = ((lr << 8) + (kc << 6) + (quad << 4)) ^ ((lr & 7) << 4);
                af = *(const bf16x8*)((char*)AsW + byte);
            } else {
                af = afh[kc - 4];
            }
            #pragma unroll
            for (int c = 0; c < 4; ++c) {
                int ct = dh * 4 + c;
                bf16x8 wfR = *(const bf16x8*)&wp[(kc * 24 + ct) * 8];
                aR[c] = __builtin_amdgcn_mfma_f32_16x16x32_bf16(wfR, af, aR[c], 0, 0, 0);
                bf16x8 wfZ = *(const bf16x8*)&wp[(kc * 24 + 8 + ct) * 8];
                aZ[c] = __builtin_amdgcn_mfma_f32_16x16x32_bf16(wfZ, af, aZ[c], 0, 0, 0);
                if (kc >= 4) {
                    bf16x8 wfH = *(const bf16x8*)&wp[(kc * 24 + 16 + ct) * 8];
                    aH[c] = __builtin_amdgcn_mfma_f32_16x16x32_bf16(wfH, af, aH[c], 0, 0, 0);
                }
            }
        }
        // r, z; fold n's h-part:  aH = bin + r*(aH + bhn)
        f32x4 rv[4], zv[4];
        #pragma unroll
        for (int c = 0; c < 4; ++c) {
            int d0 = (dh * 4 + c) * 16 + quad * 4;
            f32x4 bir = *(const f32x4*)&bih[d0],       bhr = *(const f32x4*)&bhh[d0];
            f32x4 biz = *(const f32x4*)&bih[128 + d0], bhz = *(const f32x4*)&bhh[128 + d0];
            f32x4 bin = *(const f32x4*)&bih[256 + d0], bhn = *(const f32x4*)&bhh[256 + d0];
            #pragma unroll
            for (int j = 0; j < 4; ++j) {
                rv[c][j] = sigmoidf_fast(aR[c][j] + bir[j] + bhr[j]);
                zv[c][j] = sigmoidf_fast(aZ[c][j] + biz[j] + bhz[j]);
                aH[c][j] = bin[j] + rv[c][j] * (aH[c][j] + bhn[j]);
            }
        }
        // n's m-part accumulates onto folded value via MFMA C-operand
        #pragma unroll
        for (int kc = 0; kc < 4; ++kc) {
            int byte = ((lr << 8) + (kc << 6) + (quad << 4)) ^ ((lr & 7) << 4);
            bf16x8 af = *(const bf16x8*)((char*)AsW + byte);
            #pragma unroll
            for (int c = 0; c < 4; ++c) {
                bf16x8 wfH = *(const bf16x8*)&wp[(kc * 24 + 16 + dh * 4 + c) * 8];
                aH[c] = __builtin_amdgcn_mfma_f32_16x16x32_bf16(wfH, af, aH[c], 0, 0, 0);
            }
        }
        // epilogue for this d-half
        if (valid) {
            #pragma unroll
            for (int c = 0; c < 4; ++c) {
                int d0 = (dh * 4 + c) * 16 + quad * 4;
                f32x4 h0 = *(const f32x4*)&hf[(size_t)n * 128 + d0];
                f32x4 o;
                #pragma unroll
                for (int j = 0; j < 4; ++j) {
                    float nn = tanhf_fast(aH[c][j]);
                    o[j] = (1.f - zv[c][j]) * nn + zv[c][j] * h0[j];
                }
                *(f32x4*)&out[(size_t)n * 128 + d0] = o;
            }
        }
    }
}

extern "C" void kernel_launch(void* const* d_in, const int* in_sizes, int n_in,
                              void* d_out, int out_size, void* d_ws, size_t ws_size,
                              hipStream_t stream)
{
    const float* h     = (const float*)d_in[0];
    const int*   ei    = (const int*)d_in[1];
    const int*   etype = (const int*)d_in[2];
    const float* W     = (const float*)d_in[3];
    const float* b     = (const float*)d_in[4];
    const float* wih   = (const float*)d_in[5];
    const float* whh   = (const float*)d_in[6];
    const float* bih   = (const float*)d_in[7];
    const float* bhh   = (const float*)d_in[8];
    float* out = (float*)d_out;

    int E = in_sizes[1] / 2;
    int N = in_sizes[0] / HID;
    int M8 = N * 8;
    int nbA = (M8 + 255) / 256;

    char* p = (char*)d_ws;
    auto alloc = [&](size_t bytes) { char* r = p; p += (bytes + 255) & ~(size_t)255; return r; };
    unsigned short* hbf  = (unsigned short*)alloc((size_t)N * 128 * 2);
    unsigned short* wfr  = (unsigned short*)alloc((size_t)8 * 128 * 128 * 2);
    unsigned short* wpkf = (unsigned short*)alloc((size_t)8 * 3 * 128 * 32 * 2);
    int* deg8    = (int*)alloc((size_t)M8 * 4);
    int* start8  = (int*)alloc(((size_t)M8 + 1) * 4);
    int* cur8    = (int*)alloc((size_t)M8 * 4);
    int* bsum    = (int*)alloc((size_t)nbA * 4);
    int* sortedE = (int*)alloc((size_t)E * 4);

    hipMemsetAsync(deg8, 0, (size_t)M8 * 4, stream);

    conv_h_kernel<<<(N * 128 + 255) / 256, 256, 0, stream>>>(h, hbf, N * 128);
    conv_Wfrag_kernel<<<512, 256, 0, stream>>>(W, wfr);
    conv_wpkf_kernel<<<384, 256, 0, stream>>>(wih, whh, wpkf);

    hist8_kernel<<<1024, 256, 0, stream>>>(etype, ei, E, deg8);
    scanA_kernel<<<nbA, 256, 0, stream>>>(deg8, start8, bsum, M8);
    scanBbig_kernel<<<1, 256, 0, stream>>>(bsum, nbA);
    scanC8_kernel<<<nbA, 256, 0, stream>>>(start8, bsum, cur8, M8, E);
    scatter8_kernel<<<1024, 256, 0, stream>>>(etype, ei, E, cur8, sortedE);

    fused_ggnn<<<(N + 63) / 64, 256, 0, stream>>>(hbf, h, sortedE, start8, wfr, b,
                                                  wpkf, bih, bhh, out, N);
}

// Round 2
// 650.646 us; speedup vs baseline: 1.0256x; 1.0256x over previous
//
#include <hip/hip_runtime.h>

#define HID 128

typedef __attribute__((ext_vector_type(8))) short bf16x8;
typedef __attribute__((ext_vector_type(4))) float f32x4;

__device__ __forceinline__ unsigned short f2bf(float x) {
    unsigned u = __float_as_uint(x);
    u += 0x7FFF + ((u >> 16) & 1);          // RNE
    return (unsigned short)(u >> 16);
}
__device__ __forceinline__ float bf2f(unsigned short s) {
    return __uint_as_float(((unsigned)s) << 16);
}
__device__ __forceinline__ float sigmoidf_fast(float x) {
    return 1.f / (1.f + __expf(-x));
}
__device__ __forceinline__ float tanhf_fast(float x) {
    return 1.f - 2.f / (1.f + __expf(2.f * x));
}
__device__ __forceinline__ unsigned cvt_pk_bf16(float lo, float hi) {
    unsigned r;
    asm("v_cvt_pk_bf16_f32 %0, %1, %2" : "=v"(r) : "v"(lo), "v"(hi));
    return r;
}

// ---------------- dtype prep ----------------
__global__ void conv_h_kernel(const float* __restrict__ h, unsigned short* __restrict__ hbf, int n) {
    int i = blockIdx.x * 256 + threadIdx.x;
    if (i < n) hbf[i] = f2bf(h[i]);
}

// Message weights, LANE-COALESCED fragment layout:
// wfr[(((t*4+kc)*8+cb)*64 + lane)*8 + e] = bf16( W[t][k][d] ),
//   lr=lane&15, quad=lane>>4, d=cb*16+lr, k=kc*32+quad*8+e
__global__ void conv_Wfrag_kernel(const float* __restrict__ W, unsigned short* __restrict__ wfr) {
    int i = blockIdx.x * 256 + threadIdx.x;   // 131072
    int e = i & 7, lane = (i >> 3) & 63, cb = (i >> 9) & 7, kc = (i >> 12) & 3, t = i >> 14;
    int lr = lane & 15, quad = lane >> 4;
    int d = cb * 16 + lr;
    int k = kc * 32 + quad * 8 + e;
    wfr[i] = f2bf(W[(t << 14) + (k << 7) + d]);
}

// GRU weights, LANE-COALESCED fragment layout:
// wpkf[((kc*24 + g3*8 + ct)*64 + lane)*8 + e]; kc<4 -> wih (m half), kc>=4 -> whh (h half)
//   d = ct*16+lr, kk = quad*8+e
__global__ void conv_wpkf_kernel(const float* __restrict__ wih, const float* __restrict__ whh,
                                 unsigned short* __restrict__ wpkf) {
    int i = blockIdx.x * 256 + threadIdx.x;   // 98304
    int e = i & 7, lane = (i >> 3) & 63, f = i >> 9;   // f = kc*24+g3*8+ct in 0..191
    int ct = f & 7, fg = f >> 3;                       // fg = kc*3+g3
    int g3 = fg % 3, kc = fg / 3;
    int lr = lane & 15, quad = lane >> 4;
    int d = ct * 16 + lr;
    int kk = quad * 8 + e;
    float v;
    if (kc < 4) v = wih[(g3 * 128 + d) * 128 + kc * 32 + kk];
    else        v = whh[(g3 * 128 + d) * 128 + (kc - 4) * 32 + kk];
    wpkf[i] = f2bf(v);
}

// ---------------- counting sort by key = dst*8 + type ----------------
__global__ void hist8_kernel(const int* __restrict__ etype, const int* __restrict__ ei,
                             int E, int* __restrict__ deg8) {
    int stride = gridDim.x * blockDim.x;
    for (int i = blockIdx.x * blockDim.x + threadIdx.x; i < E; i += stride)
        atomicAdd(&deg8[ei[E + i] * 8 + etype[i]], 1);
}

__global__ void scanA_kernel(const int* __restrict__ deg, int* __restrict__ start,
                             int* __restrict__ bsum, int N) {
    __shared__ int s[256];
    int i = blockIdx.x * 256 + threadIdx.x;
    int v = (i < N) ? deg[i] : 0;
    s[threadIdx.x] = v;
    __syncthreads();
    for (int off = 1; off < 256; off <<= 1) {
        int t = (threadIdx.x >= off) ? s[threadIdx.x - off] : 0;
        __syncthreads();
        s[threadIdx.x] += t;
        __syncthreads();
    }
    if (i < N) start[i] = s[threadIdx.x] - v;
    if (threadIdx.x == 255) bsum[blockIdx.x] = s[255];
}

__global__ void scanBbig_kernel(int* __restrict__ bsum, int nb) {
    __shared__ int s[256];
    int tx = threadIdx.x;
    int C = (nb + 255) / 256;
    int lo = tx * C, hi = lo + C; if (hi > nb) hi = nb;
    int sum = 0;
    for (int j = lo; j < hi; ++j) sum += bsum[j];
    s[tx] = sum;
    __syncthreads();
    for (int off = 1; off < 256; off <<= 1) {
        int t = (tx >= off) ? s[tx - off] : 0;
        __syncthreads();
        s[tx] += t;
        __syncthreads();
    }
    int run = s[tx] - sum;
    for (int j = lo; j < hi; ++j) { int v = bsum[j]; bsum[j] = run; run += v; }
}

__global__ void scanC8_kernel(int* __restrict__ start8, const int* __restrict__ bsum,
                              int* __restrict__ cur8, int M8, int E) {
    int i = blockIdx.x * 256 + threadIdx.x;
    if (i < M8) {
        int v = start8[i] + bsum[blockIdx.x];
        start8[i] = v;
        cur8[i] = v;
    }
    if (i == 0) start8[M8] = E;
}

__global__ void scatter8_kernel(const int* __restrict__ etype, const int* __restrict__ ei,
                                int E, int* __restrict__ cur8, int* __restrict__ sortedE) {
    int stride = gridDim.x * blockDim.x;
    for (int i = blockIdx.x * blockDim.x + threadIdx.x; i < E; i += stride) {
        int pos = atomicAdd(&cur8[ei[E + i] * 8 + etype[i]], 1);
        sortedE[pos] = ei[i];   // store src node id directly
    }
}

// ---------------- degree bucketing: group degree-similar nodes per wave ----------------
__global__ void degN_kernel(const int* __restrict__ start8, int* __restrict__ degN,
                            int* __restrict__ dhist, int N) {
    __shared__ int lh[256];
    int tx = threadIdx.x;
    lh[tx] = 0;
    __syncthreads();
    int i = blockIdx.x * 256 + tx;
    if (i < N) {
        int d = start8[i * 8 + 8] - start8[i * 8];
        degN[i] = d;
        int b = d > 255 ? 255 : d;
        atomicAdd(&lh[b], 1);
    }
    __syncthreads();
    if (lh[tx]) atomicAdd(&dhist[tx], lh[tx]);
}

__global__ void dscan_kernel(const int* __restrict__ dhist, int* __restrict__ dcur) {
    __shared__ int s[256];
    int tx = threadIdx.x;
    int v = dhist[tx];
    s[tx] = v;
    __syncthreads();
    for (int off = 1; off < 256; off <<= 1) {
        int t = (tx >= off) ? s[tx - off] : 0;
        __syncthreads();
        s[tx] += t;
        __syncthreads();
    }
    dcur[tx] = s[tx] - v;
}

__global__ void dscatter_kernel(const int* __restrict__ degN, int* __restrict__ dcur,
                                int* __restrict__ perm, int N) {
    __shared__ int lc[256], lb[256];
    int tx = threadIdx.x;
    int chunk = (N + gridDim.x - 1) / gridDim.x;
    int s = blockIdx.x * chunk;
    int e = s + chunk; if (e > N) e = N;
    lc[tx] = 0;
    __syncthreads();
    for (int i = s + tx; i < e; i += 256) {
        int d = degN[i]; int b = d > 255 ? 255 : d;
        atomicAdd(&lc[b], 1);
    }
    __syncthreads();
    lb[tx] = atomicAdd(&dcur[tx], lc[tx]);
    lc[tx] = 0;
    __syncthreads();
    for (int i = s + tx; i < e; i += 256) {
        int d = degN[i]; int b = d > 255 ? 255 : d;
        int p = atomicAdd(&lc[b], 1);
        perm[lb[b] + p] = i;
    }
}

// ---------------- fused aggregate -> per-type transform -> GRU ----------------
// messages[v] = sum_t W_t * (sum_{e in (v,t)} h[src_e]) + cnt(v,t)*b_t   (linearity)
// Block: 64 nodes (degree-sorted via perm), 4 waves x 16 nodes.
__global__ __launch_bounds__(256) void fused_ggnn(
    const unsigned short* __restrict__ hbf, const float* __restrict__ hf,
    const int* __restrict__ sortedE, const int* __restrict__ start8,
    const int* __restrict__ perm,
    const unsigned short* __restrict__ wfr, const float* __restrict__ bias,
    const unsigned short* __restrict__ wpkf, const float* __restrict__ bih,
    const float* __restrict__ bhh, float* __restrict__ out, int N)
{
    __shared__ unsigned short As[4][2048];   // per-wave 16x128 bf16 msg, XOR-swizzled
    __shared__ int pl[64];
    __shared__ int bnds[64][9];

    int tx = threadIdx.x;
    int n0 = blockIdx.x * 64;
    int lane = tx & 63, w = tx >> 6;
    int lr = lane & 15, quad = lane >> 4;
    int ln = w * 16 + lr;          // local node slot 0..63

    if (tx < 64) {
        int n = n0 + tx;
        pl[tx] = (n < N) ? perm[n] : -1;
    }
    __syncthreads();
    for (int i = tx; i < 576; i += 256) {
        int nl = i / 9, j = i - nl * 9;
        int pn = pl[nl];
        bnds[nl][j] = (pn >= 0) ? start8[pn * 8 + j] : 0;
    }
    __syncthreads();

    int node = pl[ln];
    bool valid = (node >= 0);
    int nc = valid ? node : 0;

    // ---- phase 1: per-type aggregate + MFMA transform ----
    f32x4 macc[8] = {};   // msg[node=lr][d = cb*16 + quad*4 + j]

    for (int t = 0; t < 8; ++t) {
        int rs = bnds[ln][t];
        int re = bnds[ln][t + 1];

        float sa[32];
        #pragma unroll
        for (int j = 0; j < 32; ++j) sa[j] = 0.f;

        // 2-deep pipelined gather (indices from L2-hot sortedE, rows from L2/L3 hbf)
        uint4 c0, c1, c2, c3;
        if (rs < re) {
            int src = sortedE[rs];
            const unsigned short* hp = hbf + ((size_t)src << 7) + (quad << 3);
            c0 = *(const uint4*)(hp);
            c1 = *(const uint4*)(hp + 32);
            c2 = *(const uint4*)(hp + 64);
            c3 = *(const uint4*)(hp + 96);
        }
        for (int r = rs; r < re; ++r) {
            uint4 p0 = c0, p1 = c1, p2 = c2, p3 = c3;
            if (r + 1 < re) {
                int src = sortedE[r + 1];
                const unsigned short* hp = hbf + ((size_t)src << 7) + (quad << 3);
                c0 = *(const uint4*)(hp);
                c1 = *(const uint4*)(hp + 32);
                c2 = *(const uint4*)(hp + 64);
                c3 = *(const uint4*)(hp + 96);
            }
            const unsigned short* q0 = (const unsigned short*)&p0;
            const unsigned short* q1 = (const unsigned short*)&p1;
            const unsigned short* q2 = (const unsigned short*)&p2;
            const unsigned short* q3 = (const unsigned short*)&p3;
            #pragma unroll
            for (int u = 0; u < 8; ++u) {
                sa[u]      += bf2f(q0[u]);
                sa[8 + u]  += bf2f(q1[u]);
                sa[16 + u] += bf2f(q2[u]);
                sa[24 + u] += bf2f(q3[u]);
            }
        }

        // transform: macc += W_t * S_t  (weight fragments now lane-coalesced: 1KB/instr)
        const unsigned short* wt = wfr + (t << 14) + (lane << 3);
        #pragma unroll
        for (int kc = 0; kc < 4; ++kc) {
            int4 au;
            au.x = (int)cvt_pk_bf16(sa[kc * 8 + 0], sa[kc * 8 + 1]);
            au.y = (int)cvt_pk_bf16(sa[kc * 8 + 2], sa[kc * 8 + 3]);
            au.z = (int)cvt_pk_bf16(sa[kc * 8 + 4], sa[kc * 8 + 5]);
            au.w = (int)cvt_pk_bf16(sa[kc * 8 + 6], sa[kc * 8 + 7]);
            bf16x8 af = *(const bf16x8*)&au;
            #pragma unroll
            for (int cb = 0; cb < 8; ++cb) {
                bf16x8 wf = *(const bf16x8*)&wt[(kc << 12) + (cb << 9)];
                macc[cb] = __builtin_amdgcn_mfma_f32_16x16x32_bf16(wf, af, macc[cb], 0, 0, 0);
            }
        }

        // count-scaled bias
        float fcnt = (float)(re - rs);
        #pragma unroll
        for (int cb = 0; cb < 8; ++cb) {
            float4 bv = *(const float4*)&bias[t * 128 + cb * 16 + quad * 4];
            macc[cb][0] += fcnt * bv.x;
            macc[cb][1] += fcnt * bv.y;
            macc[cb][2] += fcnt * bv.z;
            macc[cb][3] += fcnt * bv.w;
        }
    }

    // ---- write msg (bf16) to per-wave LDS, XOR-swizzled rows ----
    unsigned short* AsW = &As[w][0];
    #pragma unroll
    for (int cb = 0; cb < 8; ++cb) {
        uint2 v;
        v.x = cvt_pk_bf16(macc[cb][0], macc[cb][1]);
        v.y = cvt_pk_bf16(macc[cb][2], macc[cb][3]);
        int byte = (lr << 8) + (cb << 5) + (quad << 3);
        byte ^= (lr & 7) << 4;
        *(uint2*)((char*)AsW + byte) = v;
    }
    __syncthreads();

    // ---- GRU phase: sequential gates, d-half split (low live-acc count) ----
    bf16x8 afh[4];   // h fragments, cached
    {
        const unsigned short* hrow = hbf + ((size_t)nc << 7) + (quad << 3);
        #pragma unroll
        for (int k4 = 0; k4 < 4; ++k4) afh[k4] = *(const bf16x8*)&hrow[k4 * 32];
    }
    const unsigned short* wg = wpkf + (lane << 3);

    #pragma unroll
    for (int dh = 0; dh < 2; ++dh) {
        f32x4 aR[4] = {}, aZ[4] = {}, aH[4] = {};
        #pragma unroll
        for (int kc = 0; kc < 8; ++kc) {
            bf16x8 af;
            if (kc < 4) {
                int byte = ((lr << 8) + (kc << 6) + (quad << 4)) ^ ((lr & 7) << 4);
                af = *(const bf16x8*)((char*)AsW + byte);
            } else {
                af = afh[kc - 4];
            }
            #pragma unroll
            for (int c = 0; c < 4; ++c) {
                int ct = dh * 4 + c;
                bf16x8 wfR = *(const bf16x8*)&wg[(unsigned)((kc * 3 + 0) * 8 + ct) << 9];
                aR[c] = __builtin_amdgcn_mfma_f32_16x16x32_bf16(wfR, af, aR[c], 0, 0, 0);
                bf16x8 wfZ = *(const bf16x8*)&wg[(unsigned)((kc * 3 + 1) * 8 + ct) << 9];
                aZ[c] = __builtin_amdgcn_mfma_f32_16x16x32_bf16(wfZ, af, aZ[c], 0, 0, 0);
                if (kc >= 4) {
                    bf16x8 wfH = *(const bf16x8*)&wg[(unsigned)((kc * 3 + 2) * 8 + ct) << 9];
                    aH[c] = __builtin_amdgcn_mfma_f32_16x16x32_bf16(wfH, af, aH[c], 0, 0, 0);
                }
            }
        }
        // r, z; fold n's h-part:  aH = bin + r*(aH + bhn)
        f32x4 rv[4], zv[4];
        #pragma unroll
        for (int c = 0; c < 4; ++c) {
            int d0 = (dh * 4 + c) * 16 + quad * 4;
            f32x4 bir = *(const f32x4*)&bih[d0],       bhr = *(const f32x4*)&bhh[d0];
            f32x4 biz = *(const f32x4*)&bih[128 + d0], bhz = *(const f32x4*)&bhh[128 + d0];
            f32x4 bin = *(const f32x4*)&bih[256 + d0], bhn = *(const f32x4*)&bhh[256 + d0];
            #pragma unroll
            for (int j = 0; j < 4; ++j) {
                rv[c][j] = sigmoidf_fast(aR[c][j] + bir[j] + bhr[j]);
                zv[c][j] = sigmoidf_fast(aZ[c][j] + biz[j] + bhz[j]);
                aH[c][j] = bin[j] + rv[c][j] * (aH[c][j] + bhn[j]);
            }
        }
        // n's m-part accumulates onto folded value via MFMA C-operand
        #pragma unroll
        for (int kc = 0; kc < 4; ++kc) {
            int byte = ((lr << 8) + (kc << 6) + (quad << 4)) ^ ((lr & 7) << 4);
            bf16x8 af = *(const bf16x8*)((char*)AsW + byte);
            #pragma unroll
            for (int c = 0; c < 4; ++c) {
                bf16x8 wfH = *(const bf16x8*)&wg[(unsigned)((kc * 3 + 2) * 8 + dh * 4 + c) << 9];
                aH[c] = __builtin_amdgcn_mfma_f32_16x16x32_bf16(wfH, af, aH[c], 0, 0, 0);
            }
        }
        // epilogue for this d-half
        if (valid) {
            #pragma unroll
            for (int c = 0; c < 4; ++c) {
                int d0 = (dh * 4 + c) * 16 + quad * 4;
                f32x4 h0 = *(const f32x4*)&hf[(size_t)node * 128 + d0];
                f32x4 o;
                #pragma unroll
                for (int j = 0; j < 4; ++j) {
                    float nn = tanhf_fast(aH[c][j]);
                    o[j] = (1.f - zv[c][j]) * nn + zv[c][j] * h0[j];
                }
                *(f32x4*)&out[(size_t)node * 128 + d0] = o;
            }
        }
    }
}

extern "C" void kernel_launch(void* const* d_in, const int* in_sizes, int n_in,
                              void* d_out, int out_size, void* d_ws, size_t ws_size,
                              hipStream_t stream)
{
    const float* h     = (const float*)d_in[0];
    const int*   ei    = (const int*)d_in[1];
    const int*   etype = (const int*)d_in[2];
    const float* W     = (const float*)d_in[3];
    const float* b     = (const float*)d_in[4];
    const float* wih   = (const float*)d_in[5];
    const float* whh   = (const float*)d_in[6];
    const float* bih   = (const float*)d_in[7];
    const float* bhh   = (const float*)d_in[8];
    float* out = (float*)d_out;

    int E = in_sizes[1] / 2;
    int N = in_sizes[0] / HID;
    int M8 = N * 8;
    int nbA = (M8 + 255) / 256;

    char* p = (char*)d_ws;
    auto alloc = [&](size_t bytes) { char* r = p; p += (bytes + 255) & ~(size_t)255; return r; };
    unsigned short* hbf  = (unsigned short*)alloc((size_t)N * 128 * 2);
    unsigned short* wfr  = (unsigned short*)alloc((size_t)131072 * 2);
    unsigned short* wpkf = (unsigned short*)alloc((size_t)98304 * 2);
    int* deg8    = (int*)alloc((size_t)M8 * 4);
    int* start8  = (int*)alloc(((size_t)M8 + 1) * 4);
    int* cur8    = (int*)alloc((size_t)M8 * 4);
    int* bsum    = (int*)alloc((size_t)nbA * 4);
    int* sortedE = (int*)alloc((size_t)E * 4);
    int* degN    = (int*)alloc((size_t)N * 4);
    int* perm    = (int*)alloc((size_t)N * 4);
    int* dhist   = (int*)alloc(256 * 4);
    int* dcur    = (int*)alloc(256 * 4);

    hipMemsetAsync(deg8, 0, (size_t)M8 * 4, stream);
    hipMemsetAsync(dhist, 0, 256 * 4, stream);

    conv_h_kernel<<<(N * 128 + 255) / 256, 256, 0, stream>>>(h, hbf, N * 128);
    conv_Wfrag_kernel<<<512, 256, 0, stream>>>(W, wfr);
    conv_wpkf_kernel<<<384, 256, 0, stream>>>(wih, whh, wpkf);

    hist8_kernel<<<1024, 256, 0, stream>>>(etype, ei, E, deg8);
    scanA_kernel<<<nbA, 256, 0, stream>>>(deg8, start8, bsum, M8);
    scanBbig_kernel<<<1, 256, 0, stream>>>(bsum, nbA);
    scanC8_kernel<<<nbA, 256, 0, stream>>>(start8, bsum, cur8, M8, E);
    scatter8_kernel<<<1024, 256, 0, stream>>>(etype, ei, E, cur8, sortedE);

    degN_kernel<<<(N + 255) / 256, 256, 0, stream>>>(start8, degN, dhist, N);
    dscan_kernel<<<1, 256, 0, stream>>>(dhist, dcur);
    dscatter_kernel<<<256, 256, 0, stream>>>(degN, dcur, perm, N);

    fused_ggnn<<<(N + 63) / 64, 256, 0, stream>>>(hbf, h, sortedE, start8, perm, wfr, b,
                                                  wpkf, bih, bhh, out, N);
}

// Round 4
// 404.468 us; speedup vs baseline: 1.6498x; 1.6086x over previous
//
#include <hip/hip_runtime.h>

#define HID 128
#define NTY 8

typedef __attribute__((ext_vector_type(8))) short bf16x8;
typedef __attribute__((ext_vector_type(4))) float f32x4;

__device__ __forceinline__ unsigned short f2bf(float x) {
    unsigned u = __float_as_uint(x);
    u += 0x7FFF + ((u >> 16) & 1);          // RNE
    return (unsigned short)(u >> 16);
}
__device__ __forceinline__ float bf2f(unsigned short s) {
    return __uint_as_float(((unsigned)s) << 16);
}
__device__ __forceinline__ float sigmoidf_fast(float x) {
    return 1.f / (1.f + __expf(-x));
}
__device__ __forceinline__ float tanhf_fast(float x) {
    return 1.f - 2.f / (1.f + __expf(2.f * x));
}

// ---------------- fused prep: h->bf16, W->wfr frags, GRU->wpkf frags, memset-equivalents ----------------
// wfr[(((t*4+kc)*8+cb)*64 + lane)*8 + e] = bf16(W[t][k][d]), d=cb*16+(lane&15), k=kc*32+(lane>>4)*8+e
// wpkf[((kc*24+g3*8+ct)*64 + lane)*8 + e]: kc<4 -> wih, kc>=4 -> whh; d=ct*16+(lane&15), kk=(lane>>4)*8+e
__global__ void conv_all_kernel(const float* __restrict__ h, unsigned short* __restrict__ hbf, int nh,
                                const float* __restrict__ W, unsigned short* __restrict__ wfr,
                                const float* __restrict__ wih, const float* __restrict__ whh,
                                unsigned short* __restrict__ wpkf,
                                int* __restrict__ sortedT, int capE,
                                int* __restrict__ deg, int N, int* __restrict__ tcnt)
{
    int i = blockIdx.x * 256 + threadIdx.x;
    if (i < nh) { hbf[i] = f2bf(h[i]); return; }
    i -= nh;
    if (i < 131072) {
        int e = i & 7, lane = (i >> 3) & 63, cb = (i >> 9) & 7, kc = (i >> 12) & 3, t = i >> 14;
        int lr = lane & 15, quad = lane >> 4;
        int d = cb * 16 + lr;
        int k = kc * 32 + quad * 8 + e;
        wfr[i] = f2bf(W[(t << 14) + (k << 7) + d]);
        return;
    }
    i -= 131072;
    if (i < 98304) {
        int e = i & 7, lane = (i >> 3) & 63, f = i >> 9;   // f = kc*24+g3*8+ct
        int ct = f & 7, fg = f >> 3;                       // fg = kc*3+g3
        int g3 = fg % 3, kc = fg / 3;
        int lr = lane & 15, quad = lane >> 4;
        int d = ct * 16 + lr;
        int kk = quad * 8 + e;
        float v;
        if (kc < 4) v = wih[(g3 * 128 + d) * 128 + kc * 32 + kk];
        else        v = whh[(g3 * 128 + d) * 128 + (kc - 4) * 32 + kk];
        wpkf[i] = f2bf(v);
        return;
    }
    i -= 98304;
    if (i < capE) { sortedT[i] = -1; return; }
    i -= capE;
    if (i < N) { deg[i] = 0; return; }
    i -= N;
    if (i < NTY) tcnt[i] = 0;
}

// ---------------- sort bookkeeping (R0-proven) ----------------
__global__ void hist_kernel(const int* __restrict__ etype, const int* __restrict__ ei,
                            int E, int* __restrict__ tcnt, int* __restrict__ deg) {
    __shared__ int lc[NTY];
    if (threadIdx.x < NTY) lc[threadIdx.x] = 0;
    __syncthreads();
    int stride = gridDim.x * blockDim.x;
    for (int i = blockIdx.x * blockDim.x + threadIdx.x; i < E; i += stride) {
        atomicAdd(&lc[etype[i]], 1);
        if (deg) atomicAdd(&deg[ei[E + i]], 1);
    }
    __syncthreads();
    if (threadIdx.x < NTY) atomicAdd(&tcnt[threadIdx.x], lc[threadIdx.x]);
}

__global__ void scanA_kernel(const int* __restrict__ deg, int* __restrict__ start,
                             int* __restrict__ bsum, int N) {
    __shared__ int s[256];
    int i = blockIdx.x * 256 + threadIdx.x;
    int v = (i < N) ? deg[i] : 0;
    s[threadIdx.x] = v;
    __syncthreads();
    for (int off = 1; off < 256; off <<= 1) {
        int t = (threadIdx.x >= off) ? s[threadIdx.x - off] : 0;
        __syncthreads();
        s[threadIdx.x] += t;
        __syncthreads();
    }
    if (i < N) start[i] = s[threadIdx.x] - v;
    if (threadIdx.x == 255) bsum[blockIdx.x] = s[255];
}

// block-sum scan + fused 8-bin type scan (padded to 128)
__global__ void scanB_kernel(int* __restrict__ bsum, int nb,
                             const int* __restrict__ tcnt, int* __restrict__ tcur) {
    __shared__ int s[512];
    int tx = threadIdx.x;
    int v = (tx < nb) ? bsum[tx] : 0;
    s[tx] = v;
    __syncthreads();
    for (int off = 1; off < 512; off <<= 1) {
        int t = (tx >= off) ? s[tx - off] : 0;
        __syncthreads();
        s[tx] += t;
        __syncthreads();
    }
    if (tx < nb) bsum[tx] = s[tx] - v;
    if (tx == 0) {
        int off = 0;
        for (int t = 0; t < NTY; ++t) { tcur[t] = off; off += (tcnt[t] + 127) & ~127; }
    }
}

__global__ void scanC_kernel(int* __restrict__ start, const int* __restrict__ bsum,
                             int* __restrict__ dcur, int N, int E) {
    int i = blockIdx.x * 256 + threadIdx.x;
    if (i < N) {
        int v = start[i] + bsum[blockIdx.x];
        start[i] = v;
        dcur[i] = v;
    }
    if (i == 0) start[N] = E;
}

// block-aggregated scatter: 8 global tcur atomics per BLOCK (R0-proven)
__global__ __launch_bounds__(256) void scatter_agg(
    const int* __restrict__ etype, const int* __restrict__ ei, int E,
    int* __restrict__ tcur, int* __restrict__ dcur,
    int* __restrict__ sortedT, int* __restrict__ q, int mode)
{
    __shared__ int lcnt[NTY];
    __shared__ int lbase[NTY];
    int tx = threadIdx.x;
    int chunk = (E + gridDim.x - 1) / gridDim.x;
    int s = blockIdx.x * chunk;
    int e = s + chunk; if (e > E) e = E;
    if (tx < NTY) lcnt[tx] = 0;
    __syncthreads();
    for (int i = s + tx; i < e; i += 256)
        atomicAdd(&lcnt[etype[i]], 1);
    __syncthreads();
    if (tx < NTY) {
        lbase[tx] = atomicAdd(&tcur[tx], lcnt[tx]);
        lcnt[tx] = 0;
    }
    __syncthreads();
    for (int i = s + tx; i < e; i += 256) {
        int t = etype[i];
        int lp = atomicAdd(&lcnt[t], 1);
        sortedT[lbase[t] + lp] = i;
        if (mode) q[i] = atomicAdd(&dcur[ei[E + i]], 1);
    }
}

// ---------------- msg GEMM: 128-edge x 128-d tile, W direct from L2 (no K-loop barriers) ----------------
// Operand-swapped MFMA: D[d][e]; lane holds 4 consecutive d -> packed 8B stores.
__global__ __launch_bounds__(256) void msg_gemm(
    const unsigned short* __restrict__ hbf, const int* __restrict__ ei, int E,
    const int* __restrict__ etype, const unsigned short* __restrict__ wfr,
    const float* __restrict__ bias, const int* __restrict__ sortedT,
    const int* __restrict__ q, unsigned short* __restrict__ M,
    float* __restrict__ msum, int mode)
{
    __shared__ unsigned short hs[128][136];
    __shared__ int srcs[128], aux[128];
    __shared__ int stype;

    int tx = threadIdx.x;
    int base = blockIdx.x * 128;
    if (tx < 128) {
        int id = sortedT[base + tx];
        srcs[tx] = (id >= 0) ? ei[id] : -1;
        aux[tx]  = (id >= 0) ? (mode ? ei[E + id] : q[id]) : -1;
    }
    if (tx == 0) { int id0 = sortedT[base]; stype = (id0 >= 0) ? etype[id0] : -1; }
    __syncthreads();
    int t = stype;
    if (t < 0) return;

    for (int f = tx; f < 2048; f += 256) {
        int row = f >> 4, c8 = (f & 15) * 8;
        int s = srcs[row]; if (s < 0) s = 0;
        *(uint4*)&hs[row][c8] = *(const uint4*)&hbf[(size_t)s * 128 + c8];
    }
    __syncthreads();

    int lane = tx & 63, w = tx >> 6;
    int r0 = (w >> 1) * 64, c0 = (w & 1) * 64;   // r0: edge-tile base, c0: d-tile base
    int lr = lane & 15, quad = lane >> 4;
    f32x4 acc[4][4] = {};   // [rb(e-tile)][cb(d-tile)], D[d][e] per tile

    // W fragments lane-coalesced from L2: value-identical to R0's Bs fragments.
    const unsigned short* wt = wfr + (t << 14) + ((unsigned)(c0 >> 4) << 9) + (lane << 3);
    #pragma unroll
    for (int kc = 0; kc < 4; ++kc) {
        bf16x8 af[4], wf[4];
        #pragma unroll
        for (int rb = 0; rb < 4; ++rb) af[rb] = *(const bf16x8*)&hs[r0 + rb * 16 + lr][kc * 32 + quad * 8];
        #pragma unroll
        for (int cb = 0; cb < 4; ++cb) wf[cb] = *(const bf16x8*)&wt[(kc << 12) + (cb << 9)];
        #pragma unroll
        for (int rb = 0; rb < 4; ++rb)
            #pragma unroll
            for (int cb = 0; cb < 4; ++cb)
                acc[rb][cb] = __builtin_amdgcn_mfma_f32_16x16x32_bf16(wf[cb], af[rb], acc[rb][cb], 0, 0, 0);
    }

    // epilogue: e = r0+rb*16+lr, d = c0+cb*16+quad*4+reg (4 consecutive)
    float4 bv4[4];
    #pragma unroll
    for (int cb = 0; cb < 4; ++cb)
        bv4[cb] = *(const float4*)&bias[t * 128 + c0 + cb * 16 + quad * 4];

    #pragma unroll
    for (int rb = 0; rb < 4; ++rb) {
        int e = r0 + rb * 16 + lr;
        int mr = aux[e];
        if (mr < 0) continue;
        #pragma unroll
        for (int cb = 0; cb < 4; ++cb) {
            int d0 = c0 + cb * 16 + quad * 4;
            f32x4 a = acc[rb][cb];
            if (mode) {
                atomicAdd(&msum[(size_t)mr * 128 + d0 + 0], a[0] + bv4[cb].x);
                atomicAdd(&msum[(size_t)mr * 128 + d0 + 1], a[1] + bv4[cb].y);
                atomicAdd(&msum[(size_t)mr * 128 + d0 + 2], a[2] + bv4[cb].z);
                atomicAdd(&msum[(size_t)mr * 128 + d0 + 3], a[3] + bv4[cb].w);
            } else {
                uint2 v;
                v.x = (unsigned)f2bf(a[0] + bv4[cb].x) | ((unsigned)f2bf(a[1] + bv4[cb].y) << 16);
                v.y = (unsigned)f2bf(a[2] + bv4[cb].z) | ((unsigned)f2bf(a[3] + bv4[cb].w) << 16);
                *(uint2*)&M[(size_t)mr * 128 + d0] = v;
            }
        }
    }
}

// ---------------- fused seg-reduce + GRU: 64 nodes/block, sequential gates (low VGPR) ----------------
// Stage A: 4 threads/node reduce contiguous M rows, write bf16 msg to XOR-swizzled per-wave LDS.
// GRU: sequential gates + d-half split; folded n-gate via MFMA C-operand.
__global__ __launch_bounds__(256) void gru_fused(
    const unsigned short* __restrict__ M, const int* __restrict__ start,
    const float* __restrict__ msum_fb, const unsigned short* __restrict__ hbf,
    const unsigned short* __restrict__ wpkf, const float* __restrict__ bih,
    const float* __restrict__ bhh, const float* __restrict__ hf,
    float* __restrict__ out, int N, int mode)
{
    __shared__ unsigned short As[4][2048];   // per-wave 16x128 bf16 msg; row lr linear in d, byte ^ ((lr&7)<<4)

    int tx = threadIdx.x;
    int n0 = blockIdx.x * 64;

    // ---- stage A ----
    {
        int node = tx >> 2, qd = tx & 3;
        int n = n0 + node;
        int nc = (n < N) ? n : N - 1;
        float a[32];
        #pragma unroll
        for (int j = 0; j < 32; ++j) a[j] = 0.f;
        if (mode == 0) {
            int s = start[nc], e = start[nc + 1];
            uint4 c0v, c1v, c2v, c3v;
            if (s < e) {
                const unsigned short* Mp = M + (size_t)s * 128 + qd * 32;
                c0v = *(const uint4*)(Mp);
                c1v = *(const uint4*)(Mp + 8);
                c2v = *(const uint4*)(Mp + 16);
                c3v = *(const uint4*)(Mp + 24);
            }
            for (int r = s; r < e; ++r) {
                uint4 p0 = c0v, p1 = c1v, p2 = c2v, p3 = c3v;
                if (r + 1 < e) {
                    const unsigned short* Mn = M + (size_t)(r + 1) * 128 + qd * 32;
                    c0v = *(const uint4*)(Mn);
                    c1v = *(const uint4*)(Mn + 8);
                    c2v = *(const uint4*)(Mn + 16);
                    c3v = *(const uint4*)(Mn + 24);
                }
                const unsigned short* q0 = (const unsigned short*)&p0;
                const unsigned short* q1 = (const unsigned short*)&p1;
                const unsigned short* q2 = (const unsigned short*)&p2;
                const unsigned short* q3 = (const unsigned short*)&p3;
                #pragma unroll
                for (int u = 0; u < 8; ++u) {
                    a[u]      += bf2f(q0[u]);
                    a[8 + u]  += bf2f(q1[u]);
                    a[16 + u] += bf2f(q2[u]);
                    a[24 + u] += bf2f(q3[u]);
                }
            }
        } else {
            #pragma unroll
            for (int j = 0; j < 8; ++j) {
                float4 v = *(const float4*)&msum_fb[(size_t)nc * 128 + qd * 32 + j * 4];
                a[j * 4 + 0] = v.x; a[j * 4 + 1] = v.y; a[j * 4 + 2] = v.z; a[j * 4 + 3] = v.w;
            }
        }
        unsigned short tmp[32];
        #pragma unroll
        for (int j = 0; j < 32; ++j) tmp[j] = f2bf(a[j]);
        int lrw = node & 15, wv = node >> 4;
        #pragma unroll
        for (int j = 0; j < 4; ++j) {
            int byte = (lrw << 8) + (qd << 6) + (j << 4);
            byte ^= (lrw & 7) << 4;
            *(uint4*)((char*)&As[wv][0] + byte) = *(const uint4*)&tmp[j * 8];
        }
    }
    __syncthreads();

    // ---- GRU phase ----
    int lane = tx & 63, w = tx >> 6;
    int lr = lane & 15, quad = lane >> 4;
    int node = n0 + w * 16 + lr;
    bool valid = node < N;
    int nc = valid ? node : (N - 1);
    unsigned short* AsW = &As[w][0];

    bf16x8 afh[4];   // h fragments, cached
    {
        const unsigned short* hrow = hbf + ((size_t)nc << 7) + (quad << 3);
        #pragma unroll
        for (int k4 = 0; k4 < 4; ++k4) afh[k4] = *(const bf16x8*)&hrow[k4 * 32];
    }
    const unsigned short* wg = wpkf + (lane << 3);

    #pragma unroll
    for (int dh = 0; dh < 2; ++dh) {
        f32x4 aR[4] = {}, aZ[4] = {}, aH[4] = {};
        #pragma unroll
        for (int kc = 0; kc < 8; ++kc) {
            bf16x8 af;
            if (kc < 4) {
                int byte = ((lr << 8) + (kc << 6) + (quad << 4)) ^ ((lr & 7) << 4);
                af = *(const bf16x8*)((char*)AsW + byte);
            } else {
                af = afh[kc - 4];
            }
            #pragma unroll
            for (int c = 0; c < 4; ++c) {
                int ct = dh * 4 + c;
                bf16x8 wfR = *(const bf16x8*)&wg[(unsigned)((kc * 3 + 0) * 8 + ct) << 9];
                aR[c] = __builtin_amdgcn_mfma_f32_16x16x32_bf16(wfR, af, aR[c], 0, 0, 0);
                bf16x8 wfZ = *(const bf16x8*)&wg[(unsigned)((kc * 3 + 1) * 8 + ct) << 9];
                aZ[c] = __builtin_amdgcn_mfma_f32_16x16x32_bf16(wfZ, af, aZ[c], 0, 0, 0);
                if (kc >= 4) {
                    bf16x8 wfH = *(const bf16x8*)&wg[(unsigned)((kc * 3 + 2) * 8 + ct) << 9];
                    aH[c] = __builtin_amdgcn_mfma_f32_16x16x32_bf16(wfH, af, aH[c], 0, 0, 0);
                }
            }
        }
        // r, z; fold n's h-part:  aH = bin + r*(aH + bhn)
        f32x4 rv[4], zv[4];
        #pragma unroll
        for (int c = 0; c < 4; ++c) {
            int d0 = (dh * 4 + c) * 16 + quad * 4;
            f32x4 bir = *(const f32x4*)&bih[d0],       bhr = *(const f32x4*)&bhh[d0];
            f32x4 biz = *(const f32x4*)&bih[128 + d0], bhz = *(const f32x4*)&bhh[128 + d0];
            f32x4 bin = *(const f32x4*)&bih[256 + d0], bhn = *(const f32x4*)&bhh[256 + d0];
            #pragma unroll
            for (int j = 0; j < 4; ++j) {
                rv[c][j] = sigmoidf_fast(aR[c][j] + bir[j] + bhr[j]);
                zv[c][j] = sigmoidf_fast(aZ[c][j] + biz[j] + bhz[j]);
                aH[c][j] = bin[j] + rv[c][j] * (aH[c][j] + bhn[j]);
            }
        }
        // n's m-part accumulates onto folded value via MFMA C-operand
        #pragma unroll
        for (int kc = 0; kc < 4; ++kc) {
            int byte = ((lr << 8) + (kc << 6) + (quad << 4)) ^ ((lr & 7) << 4);
            bf16x8 af = *(const bf16x8*)((char*)AsW + byte);
            #pragma unroll
            for (int c = 0; c < 4; ++c) {
                bf16x8 wfH = *(const bf16x8*)&wg[(unsigned)((kc * 3 + 2) * 8 + dh * 4 + c) << 9];
                aH[c] = __builtin_amdgcn_mfma_f32_16x16x32_bf16(wfH, af, aH[c], 0, 0, 0);
            }
        }
        // epilogue for this d-half
        if (valid) {
            #pragma unroll
            for (int c = 0; c < 4; ++c) {
                int d0 = (dh * 4 + c) * 16 + quad * 4;
                f32x4 h0 = *(const f32x4*)&hf[(size_t)node * 128 + d0];
                f32x4 o;
                #pragma unroll
                for (int j = 0; j < 4; ++j) {
                    float nn = tanhf_fast(aH[c][j]);
                    o[j] = (1.f - zv[c][j]) * nn + zv[c][j] * h0[j];
                }
                *(f32x4*)&out[(size_t)node * 128 + d0] = o;
            }
        }
    }
}

extern "C" void kernel_launch(void* const* d_in, const int* in_sizes, int n_in,
                              void* d_out, int out_size, void* d_ws, size_t ws_size,
                              hipStream_t stream)
{
    const float* h     = (const float*)d_in[0];
    const int*   ei    = (const int*)d_in[1];
    const int*   etype = (const int*)d_in[2];
    const float* W     = (const float*)d_in[3];
    const float* b     = (const float*)d_in[4];
    const float* wih   = (const float*)d_in[5];
    const float* whh   = (const float*)d_in[6];
    const float* bih   = (const float*)d_in[7];
    const float* bhh   = (const float*)d_in[8];
    float* out = (float*)d_out;

    int E = in_sizes[1] / 2;
    int N = in_sizes[0] / HID;
    int capE = ((E + 127) / 128 + NTY) * 128;
    int nbA = (N + 255) / 256;

    char* p = (char*)d_ws;
    auto alloc = [&](size_t bytes) { char* r = p; p += (bytes + 255) & ~(size_t)255; return r; };
    unsigned short* hbf  = (unsigned short*)alloc((size_t)N * 128 * 2);
    unsigned short* wfr  = (unsigned short*)alloc((size_t)131072 * 2);
    unsigned short* wpkf = (unsigned short*)alloc((size_t)98304 * 2);
    int* tcnt    = (int*)alloc(NTY * 4);
    int* tcur    = (int*)alloc(NTY * 4);
    int* sortedT = (int*)alloc((size_t)capE * 4);
    unsigned short* M = (unsigned short*)alloc((size_t)E * 128 * 2);
    int* q     = (int*)alloc((size_t)E * 4);
    int* deg   = (int*)alloc((size_t)N * 4);
    int* start = (int*)alloc((size_t)(N + 1) * 4);
    int* dcur  = (int*)alloc((size_t)N * 4);
    int* bsum  = (int*)alloc(512 * 4);
    int mode = ((size_t)(p - (char*)d_ws) <= ws_size) ? 0 : 1;

    if (mode == 1) hipMemsetAsync(out, 0, (size_t)N * 128 * 4, stream);

    int totalConv = N * 128 + 131072 + 98304 + capE + N + NTY;
    conv_all_kernel<<<(totalConv + 255) / 256, 256, 0, stream>>>(
        h, hbf, N * 128, W, wfr, wih, whh, wpkf, sortedT, capE, deg, N, tcnt);

    hist_kernel<<<1024, 256, 0, stream>>>(etype, ei, E, tcnt, (mode == 0) ? deg : nullptr);
    if (mode == 0)
        scanA_kernel<<<nbA, 256, 0, stream>>>(deg, start, bsum, N);
    scanB_kernel<<<1, 512, 0, stream>>>(bsum, nbA, tcnt, tcur);
    if (mode == 0)
        scanC_kernel<<<nbA, 256, 0, stream>>>(start, bsum, dcur, N, E);
    scatter_agg<<<256, 256, 0, stream>>>(etype, ei, E, tcur, dcur, sortedT, q, (mode == 0) ? 1 : 0);

    msg_gemm<<<capE / 128, 256, 0, stream>>>(hbf, ei, E, etype, wfr, b, sortedT, q, M, out, mode);
    gru_fused<<<(N + 63) / 64, 256, 0, stream>>>(M, start, out, hbf, wpkf, bih, bhh, h, out, N, mode);
}